// Round 3
// baseline (543.869 us; speedup 1.0000x reference)
//
#include <hip/hip_runtime.h>
#include <math.h>

#define NN 1152
#define DD 64
#define NSK 2016
#define NB 16
#define NROWS (NB*1024)
#define GPARTS 6
#define KPARTS 6
#define VNBLK 32
#define VBLKS (VNBLK*KPARTS)   // 192 vproj GEMM blocks

// hi/lo bf16 matrix planes for expm
#define STR 72                 // shorts per plane row (bank-conflict-friendly)
#define PLANE (64*STR)         // 4608 shorts
#define MATS  (2*PLANE)        // hi plane + lo plane per logical matrix

typedef short bf16x8 __attribute__((ext_vector_type(8)));
typedef short bf16x4 __attribute__((ext_vector_type(4)));
typedef float f32x4  __attribute__((ext_vector_type(4)));

__device__ __forceinline__ short bfr(float f){
  unsigned u = __float_as_uint(f);
  u += 0x7fffu + ((u >> 16) & 1u);
  return (short)(u >> 16);
}
__device__ __forceinline__ float htof(short h){
  return __uint_as_float(((unsigned)(unsigned short)h) << 16);
}
__device__ __forceinline__ float ld_hl(const short* mat, int off){
  return htof(mat[off]) + htof(mat[PLANE + off]);
}
__device__ __forceinline__ void st_hl(short* mat, int off, float v){
  const short h = bfr(v);
  mat[off] = h;
  mat[PLANE + off] = bfr(v - htof(h));
}

// ================= K1: vproj as MFMA GEMM (blocks 0..191) + partial gram (192..197) ==========
__global__ __launch_bounds__(256) void k_pre(const float* __restrict__ cond, const float* __restrict__ W,
                                             float* __restrict__ vpart,
                                             const float* __restrict__ P, float* __restrict__ Gpart){
  __shared__ float Ps[64*68];
  const int tid = threadIdx.x;
  if (blockIdx.x < VBLKS){
    const int nb = blockIdx.x / KPARTS;
    const int kp = blockIdx.x % KPARTS;
    const int lane = tid & 63, wid = tid >> 6;
    const int m = lane & 15, quad = lane >> 4;
    const int n0 = nb*64 + wid*16;
    if (n0 >= NSK) return;            // tail tiles of last N-block
    f32x4 acc = {0.f,0.f,0.f,0.f};
    const float* crow = &cond[m*NN + kp*192 + quad*8];
    const float* wrow = &W[(n0 + m)*NN + kp*192 + quad*8];
    #pragma unroll
    for (int c = 0; c < 6; ++c){
      const float4 ca = *(const float4*)(crow + c*32);
      const float4 cb = *(const float4*)(crow + c*32 + 4);
      const float4 wa = *(const float4*)(wrow + c*32);
      const float4 wb = *(const float4*)(wrow + c*32 + 4);
      bf16x8 a, b;
      const float cv[8] = {ca.x,ca.y,ca.z,ca.w,cb.x,cb.y,cb.z,cb.w};
      const float wv[8] = {wa.x,wa.y,wa.z,wa.w,wb.x,wb.y,wb.z,wb.w};
      #pragma unroll
      for (int j = 0; j < 8; ++j){
        const float xv = cv[j];
        a[j] = bfr(xv / (1.f + __expf(-xv)));
        b[j] = bfr(wv[j]);
      }
      acc = __builtin_amdgcn_mfma_f32_16x16x32_bf16(a, b, acc, 0, 0, 0);
    }
    #pragma unroll
    for (int r = 0; r < 4; ++r)
      vpart[(kp*16 + quad*4 + r)*NSK + n0 + m] = acc[r];
  } else {
    // ---- partial gram: block p covers rows p*192 .. p*192+191 (3 chunks of 64)
    const int p = blockIdx.x - VBLKS;
    const int lr = tid >> 4, lc = (tid & 15) * 4;
    const int ti = tid >> 4, tj = tid & 15;
    float acc[4][4];
    #pragma unroll
    for (int i=0;i<4;++i){
      #pragma unroll
      for (int j=0;j<4;++j) acc[i][j]=0.f;
    }
    for (int ch = 0; ch < 3; ++ch){
      const int nn0 = p*192 + ch*64;
      __syncthreads();
      #pragma unroll
      for (int ii = 0; ii < 4; ++ii){
        const float4 pv = *(const float4*)&P[(nn0 + lr + 16*ii)*DD + lc];
        *(float4*)&Ps[(lr + 16*ii)*68 + lc] = pv;
      }
      __syncthreads();
      for (int r = 0; r < 64; ++r){
        const float4 a = *(const float4*)&Ps[r*68 + ti*4];
        const float4 b = *(const float4*)&Ps[r*68 + tj*4];
        const float av[4] = {a.x,a.y,a.z,a.w};
        const float bv[4] = {b.x,b.y,b.z,b.w};
        #pragma unroll
        for (int i=0;i<4;++i){
          #pragma unroll
          for (int j=0;j<4;++j) acc[i][j] = fmaf(av[i], bv[j], acc[i][j]);
        }
      }
    }
    float* g = &Gpart[p*DD*DD];
    #pragma unroll
    for (int i=0;i<4;++i){
      float4 ov = make_float4(acc[i][0], acc[i][1], acc[i][2], acc[i][3]);
      *(float4*)&g[(ti*4+i)*DD + tj*4] = ov;
    }
  }
}

// ================= K2: register-wave QR (block 16) + MFMA hi/lo expm (blocks 0..15) ==========
__device__ void qr_wave(const float* __restrict__ Gpart, const float* __restrict__ P,
                        float* __restrict__ Rout){
  const int j = threadIdx.x; // lane = column j
  float Gc[DD], Wc[DD], Rc[DD];
  #pragma unroll
  for (int i = 0; i < DD; ++i){
    float g = 0.f;
    #pragma unroll
    for (int p = 0; p < GPARTS; ++p) g += Gpart[p*4096 + i*DD + j];
    Gc[i] = g;
    Wc[i] = P[i*DD + j];
  }
  #pragma unroll
  for (int k = 0; k < DD; ++k){
    const float gkk = __shfl(Gc[k], k);
    const float wkk = __shfl(Wc[k], k);
    const float beta = (wkk >= 0.f) ? -sqrtf(gkk) : sqrtf(gkk);
    const float wkj = Wc[k];
    const float dj  = Gc[k] - beta*wkj;
    const float cj  = dj / (beta*(beta - wkk));
    float rkj = wkj + dj/beta;
    if (j == k) rkj = beta;
    if (j <  k) rkj = 0.f;
    Rc[k] = rkj;
    #pragma unroll
    for (int i = k+1; i < DD; ++i){
      const float wik = __shfl(Wc[i], k);   // column k of Wt lives in lane k
      const float rki = __shfl(rkj, i);     // R[k][i] lives in lane i
      Wc[i] = fmaf(-cj,  wik, Wc[i]);
      Gc[i] = fmaf(-rki, rkj, Gc[i]);
    }
  }
  #pragma unroll
  for (int i = 0; i < DD; ++i) Rout[i*DD + j] = Rc[i];
}

// C = sgn * (A @ effB) computed in bf16 hi/lo compensated MFMA (fp32 accum).
//   Arm: row-major hi/lo planes (a-frag: row = lane&15, k contiguous)
//   Bcm: plane whose ROW r holds column r of effB^T... i.e. reading plane row c
//        supplies effB[k][c]; pass a cm-plane for effB = M, or an rm-plane of a
//        skew matrix Z for effB = Z^T = -Z (fold sign into sgn).
//   EPI: v += (row==col)*cd + cs*S[row][col] + cp*P2[row][col] (rm reads).
//   WRM/WCM: write row-major / col-major dest planes. Dest may alias an operand:
//   all reads complete before the mid-barrier, writes after.
template<bool WRM, bool WCM, bool EPI>
__device__ __forceinline__ void mm64(const short* Arm, const short* Bcm,
                                     short* Drm, short* Dcm, const float sgn,
                                     const short* Sm, const short* P2m,
                                     const float cd, const float cs, const float cp,
                                     const int tid){
  __syncthreads();
  const int lane = tid & 63, wid = tid >> 6;
  const int m = lane & 15, quad = lane >> 4;
  const int r0 = (wid >> 1) * 32, c0 = (wid & 1) * 32;
  f32x4 acc[2][2];
  #pragma unroll
  for (int tr = 0; tr < 2; ++tr)
    #pragma unroll
    for (int tc = 0; tc < 2; ++tc)
      acc[tr][tc] = (f32x4){0.f,0.f,0.f,0.f};
  #pragma unroll
  for (int kb = 0; kb < 2; ++kb){
    bf16x8 ah[2], al[2], bh[2], bl[2];
    #pragma unroll
    for (int t = 0; t < 2; ++t){
      const short* ap = &Arm[(r0 + t*16 + m)*STR + kb*32 + quad*8];
      ah[t] = *(const bf16x8*)ap;
      al[t] = *(const bf16x8*)(ap + PLANE);
      const short* bp = &Bcm[(c0 + t*16 + m)*STR + kb*32 + quad*8];
      bh[t] = *(const bf16x8*)bp;
      bl[t] = *(const bf16x8*)(bp + PLANE);
    }
    #pragma unroll
    for (int tr = 0; tr < 2; ++tr){
      #pragma unroll
      for (int tc = 0; tc < 2; ++tc){
        acc[tr][tc] = __builtin_amdgcn_mfma_f32_16x16x32_bf16(ah[tr], bh[tc], acc[tr][tc], 0,0,0);
        acc[tr][tc] = __builtin_amdgcn_mfma_f32_16x16x32_bf16(ah[tr], bl[tc], acc[tr][tc], 0,0,0);
        acc[tr][tc] = __builtin_amdgcn_mfma_f32_16x16x32_bf16(al[tr], bh[tc], acc[tr][tc], 0,0,0);
        acc[tr][tc] = __builtin_amdgcn_mfma_f32_16x16x32_bf16(al[tr], bl[tc], acc[tr][tc], 0,0,0);
      }
    }
  }
  __syncthreads();   // all operand reads done; dest may alias an operand
  #pragma unroll
  for (int tr = 0; tr < 2; ++tr){
    #pragma unroll
    for (int tc = 0; tc < 2; ++tc){
      #pragma unroll
      for (int q = 0; q < 4; ++q){
        const int row = r0 + tr*16 + quad*4 + q;
        const int col = c0 + tc*16 + m;
        float v = sgn * acc[tr][tc][q];
        if (EPI){
          const int o = row*STR + col;
          v += (row==col ? cd : 0.f) + cs*ld_hl(Sm, o) + cp*ld_hl(P2m, o);
        }
        const short h = bfr(v);
        const short l = bfr(v - htof(h));
        if (WRM){ Drm[row*STR + col] = h; Drm[PLANE + row*STR + col] = l; }
        if (WCM){ Dcm[col*STR + row] = h; Dcm[PLANE + col*STR + row] = l; }
      }
    }
  }
  __syncthreads();
}

__global__ __launch_bounds__(256,1) void k_setup(const float* __restrict__ Gpart, const float* __restrict__ P,
                                                 float* __restrict__ Rout,
                                                 const float* __restrict__ vpart, const float* __restrict__ bias,
                                                 float* __restrict__ Mg){
  __shared__ __align__(16) short smem[5*MATS];
  __shared__ float scl_s;
  __shared__ int   ssh_s;
  const int tid = threadIdx.x;
  if (blockIdx.x == NB){
    if (tid >= 64) return;
    qr_wave(Gpart, P, Rout);
    return;
  }
  const int b = blockIdx.x;
  short* S  = smem;             // skew (rm)
  short* P2 = smem + 1*MATS;    // B^2 (rm, symmetric)
  short* P3 = smem + 2*MATS;    // B^3 (rm, skew)
  short* Qb = smem + 3*MATS;    // poly accum (cm) -> cur rm
  short* Xb = smem + 4*MATS;    // poly accum (cm) -> cur cm

  // ---- build skew A (unscaled) into S (hi/lo planes)
  for (int i = tid; i < MATS; i += 256) S[i] = 0;
  __syncthreads();
  for (int idx = tid; idx < NSK; idx += 256){
    int i = (int)((127.0f - sqrtf(16129.0f - 8.0f*(float)idx)) * 0.5f);
    while (i*(127 - i)/2 > idx) --i;
    while ((i+1)*(127 - (i+1))/2 <= idx) ++i;
    const int jj = idx - i*(127 - i)/2 + i + 1;
    float val = bias[idx];
    #pragma unroll
    for (int p = 0; p < KPARTS; ++p) val += vpart[(p*16 + b)*NSK + idx];
    st_hl(S, i*STR + jj,  val);
    st_hl(S, jj*STR + i, -val);
  }
  __syncthreads();
  // ---- 1-norm -> scaling (P2 space as scratch)
  {
    float* red = (float*)P2;
    const int c = tid & 63, g = tid >> 6;
    float s = 0.f;
    for (int r = g*16; r < g*16 + 16; ++r) s += fabsf(ld_hl(S, r*STR + c));
    red[g*64 + c] = s;
    __syncthreads();
    if (tid < 64){
      float mx = red[c] + red[64 + c] + red[128 + c] + red[192 + c];
      #pragma unroll
      for (int off = 32; off > 0; off >>= 1) mx = fmaxf(mx, __shfl_xor(mx, off));
      if (tid == 0){
        int s2 = 0; float scale = 1.f;
        while (mx > 1.0f && s2 < 40){ mx *= 0.5f; scale *= 0.5f; ++s2; }
        ssh_s = s2; scl_s = scale;
      }
    }
    __syncthreads();
  }
  const float scale = scl_s;
  const int   sq    = ssh_s;
  // ---- exact pow2 scale in place (hi/lo split preserved)
  for (int idx = tid; idx < 4096; idx += 256){
    const int off = (idx >> 6)*STR + (idx & 63);
    S[off]        = bfr(htof(S[off])        * scale);
    S[PLANE+off]  = bfr(htof(S[PLANE+off])  * scale);
  }
  // ---- P2 = S*S ; P3 = P2*S  (B-operand = S.rm, effB = S^T = -S -> sgn -1)
  mm64<true,false,false>(S,  S, P2, nullptr, -1.f, nullptr, nullptr, 0.f,0.f,0.f, tid);
  mm64<true,false,false>(P2, S, P3, nullptr, -1.f, nullptr, nullptr, 0.f,0.f,0.f, tid);
  // ---- Qb(cm) = I/720 + S/5040 + P2/40320 + P3/362880  (reads at plane off (c,r))
  for (int idx = tid; idx < 4096; idx += 256){
    const int r = idx & 63, c = idx >> 6;
    const int o = c*STR + r;     // plane[c][r] == element (row=r, col=c) for cm dest
    const float sv  = ld_hl(S,  o);   // S[c][r]  = -S[r][c]
    const float p2v = ld_hl(P2, o);   // P2 symmetric
    const float p3v = ld_hl(P3, o);   // P3 skew
    const float v = (r==c ? (1.f/720.f) : 0.f) - sv*(1.f/5040.f) + p2v*(1.f/40320.f) - p3v*(1.f/362880.f);
    st_hl(Qb, o, v);
  }
  // ---- Xb(cm) = P3*Qb + I/6 + S/24 + P2/120
  mm64<false,true,true>(P3, Qb, nullptr, Xb, 1.f, S, P2, 1.f/6.f, 1.f/24.f, 1.f/120.f, tid);
  // ---- cur = P3*Xb + I + S + P2/2  -> rm into Qb space, cm into Xb space
  mm64<true,true,true>(P3, Xb, Qb, Xb, 1.f, S, P2, 1.f, 1.f, 0.5f, tid);
  // ---- squarings: cur = cur*cur (dual rm/cm), ping-pong (Qb,Xb) <-> (S,P2)
  short* crm = Qb; short* ccm = Xb;
  short* orm = S;  short* ocm = P2;
  for (int r = 0; r < sq; ++r){
    mm64<true,true,false>(crm, ccm, orm, ocm, 1.f, nullptr, nullptr, 0.f,0.f,0.f, tid);
    short* t;
    t = crm; crm = orm; orm = t;
    t = ccm; ccm = ocm; ocm = t;
  }
  // ---- Mg = cur - I
  for (int idx = tid; idx < 4096; idx += 256){
    const int r = idx >> 6, c = idx & 63;
    Mg[b*4096 + idx] = ld_hl(crm, r*STR + c) - (r==c ? 1.f : 0.f);
  }
}

// ================= K3: solve u.R = p per row; emit U bf16 (row-major) + U^T bf16 ==========
__global__ __launch_bounds__(64) void k_solveU(const float* __restrict__ P, const float* __restrict__ Rg,
                                               short* __restrict__ Ubf, short* __restrict__ Utbf){
  __shared__ float Rs[DD*DD];
  __shared__ float Ps[DD*65];
  __shared__ float rd[DD];
  const int tid = threadIdx.x;
  const int n0 = blockIdx.x * DD;
  for (int r = 0; r < DD; ++r){
    Rs[r*DD + tid] = Rg[r*DD + tid];
    Ps[r*65 + tid] = P[(n0 + r)*DD + tid];
  }
  rd[tid] = 1.f / Rg[tid*DD + tid];
  __syncthreads();
  float u[DD];
  #pragma unroll
  for (int j = 0; j < DD; ++j){
    float s0 = Ps[tid*65 + j], s1 = 0.f;
    #pragma unroll
    for (int l = 0; l + 1 < j; l += 2){
      s0 = fmaf(-u[l],   Rs[l*DD + j],     s0);
      s1 = fmaf(-u[l+1], Rs[(l+1)*DD + j], s1);
    }
    if (j & 1) s0 = fmaf(-u[j-1], Rs[(j-1)*DD + j], s0);
    u[j] = (s0 + s1) * rd[j];
  }
  #pragma unroll
  for (int d = 0; d < DD; ++d)
    Utbf[d*NN + n0 + tid] = bfr(u[d]);
  #pragma unroll
  for (int j8 = 0; j8 < 8; ++j8){
    bf16x8 pk;
    #pragma unroll
    for (int jj = 0; jj < 8; ++jj) pk[jj] = bfr(u[j8*8 + jj]);
    *(bf16x8*)&Ubf[(n0 + tid)*DD + j8*8] = pk;
  }
}

// ================= K4a: z = x.U ; w = z.(R-I) -> wg bf16 ==========
__global__ __launch_bounds__(512,1) void k_zw(const float* __restrict__ x, const short* __restrict__ Utbf,
                                              const float* __restrict__ Mg, short* __restrict__ wg){
  __shared__ float zs[64*68];
  __shared__ float Ms[64*68];
  const int tid  = threadIdx.x;
  const int lane = tid & 63, wid = tid >> 6;
  const int row0 = blockIdx.x * 64;
  const int bb   = row0 >> 10;
  const int m    = lane & 15, quad = lane >> 4;
  for (int idx = tid; idx < 64*64; idx += 512)
    Ms[(idx>>6)*68 + (idx&63)] = Mg[bb*4096 + idx];

  // ---- phase 1: z = x_tile @ U   (wave: rows (wid&3)*16, cols (wid>>2)*32)
  const int r0 = (wid & 3) * 16;
  const int c0 = (wid >> 2) * 32;
  f32x4 acc0 = {0.f,0.f,0.f,0.f}, acc1 = {0.f,0.f,0.f,0.f};
  const float* xrow = &x[(row0 + r0 + m)*NN + quad*8];
  const short* ut0  = &Utbf[(c0      + m)*NN + quad*8];
  const short* ut1  = &Utbf[(c0 + 16 + m)*NN + quad*8];
  float4 xa = *(const float4*)(xrow);
  float4 xb = *(const float4*)(xrow + 4);
  bf16x8 b0 = *(const bf16x8*)(ut0);
  bf16x8 b1 = *(const bf16x8*)(ut1);
  for (int kc = 0; kc < NN; kc += 32){
    float4 nxa, nxb; bf16x8 nb0, nb1;
    if (kc + 32 < NN){
      nxa = *(const float4*)(xrow + kc + 32);
      nxb = *(const float4*)(xrow + kc + 36);
      nb0 = *(const bf16x8*)(ut0 + kc + 32);
      nb1 = *(const bf16x8*)(ut1 + kc + 32);
    }
    bf16x8 a;
    a[0]=bfr(xa.x); a[1]=bfr(xa.y); a[2]=bfr(xa.z); a[3]=bfr(xa.w);
    a[4]=bfr(xb.x); a[5]=bfr(xb.y); a[6]=bfr(xb.z); a[7]=bfr(xb.w);
    acc0 = __builtin_amdgcn_mfma_f32_16x16x32_bf16(a, b0, acc0, 0, 0, 0);
    acc1 = __builtin_amdgcn_mfma_f32_16x16x32_bf16(a, b1, acc1, 0, 0, 0);
    xa = nxa; xb = nxb; b0 = nb0; b1 = nb1;
  }
  #pragma unroll
  for (int q = 0; q < 4; ++q){
    zs[(r0 + quad*4 + q)*68 + c0      + m] = acc0[q];
    zs[(r0 + quad*4 + q)*68 + c0 + 16 + m] = acc1[q];
  }
  __syncthreads();

  // ---- phase 2: w = z @ M (fp32), store bf16 to global
  const int r  = tid >> 3;
  const int cc = (tid & 7) * 8;
  float w0[8];
  #pragma unroll
  for (int jj = 0; jj < 8; ++jj) w0[jj] = 0.f;
  for (int k = 0; k < 64; ++k){
    const float zr = zs[r*68 + k];
    const float4 m0 = *(const float4*)&Ms[k*68 + cc];
    const float4 m1 = *(const float4*)&Ms[k*68 + cc + 4];
    w0[0] = fmaf(zr, m0.x, w0[0]); w0[1] = fmaf(zr, m0.y, w0[1]);
    w0[2] = fmaf(zr, m0.z, w0[2]); w0[3] = fmaf(zr, m0.w, w0[3]);
    w0[4] = fmaf(zr, m1.x, w0[4]); w0[5] = fmaf(zr, m1.y, w0[5]);
    w0[6] = fmaf(zr, m1.z, w0[6]); w0[7] = fmaf(zr, m1.w, w0[7]);
  }
  bf16x8 pk;
  #pragma unroll
  for (int jj = 0; jj < 8; ++jj) pk[jj] = bfr(w0[jj]);
  *(bf16x8*)&wg[(row0 + r)*DD + cc] = pk;
}

// ================= K4b: out = x + w @ U^T  (pure streaming) ==========
__global__ __launch_bounds__(256) void k_out(const float* __restrict__ x, const short* __restrict__ Ubf,
                                             const short* __restrict__ wg, float* __restrict__ out){
  const int tid  = threadIdx.x;
  const int lane = tid & 63, wid = tid >> 6;
  const int row0 = blockIdx.x * 16;
  const int m    = lane & 15, quad = lane >> 4;
  const int q4   = quad * 4;
  bf16x8 wa0 = *(const bf16x8*)&wg[(row0 + m)*DD +      quad*8];
  bf16x8 wa1 = *(const bf16x8*)&wg[(row0 + m)*DD + 32 + quad*8];
  bf16x8 ub0 = *(const bf16x8*)&Ubf[(wid*16 + m)*DD +      quad*8];
  bf16x8 ub1 = *(const bf16x8*)&Ubf[(wid*16 + m)*DD + 32 + quad*8];
  float xq0 = x[(row0 + q4 + 0)*NN + wid*16 + m];
  float xq1 = x[(row0 + q4 + 1)*NN + wid*16 + m];
  float xq2 = x[(row0 + q4 + 2)*NN + wid*16 + m];
  float xq3 = x[(row0 + q4 + 3)*NN + wid*16 + m];
  for (int it = 0; it < 18; ++it){
    const int n0 = (wid + 4*it) * 16;
    f32x4 acc = {0.f,0.f,0.f,0.f};
    acc = __builtin_amdgcn_mfma_f32_16x16x32_bf16(wa0, ub0, acc, 0, 0, 0);
    acc = __builtin_amdgcn_mfma_f32_16x16x32_bf16(wa1, ub1, acc, 0, 0, 0);
    const float o0 = xq0 + acc[0];
    const float o1 = xq1 + acc[1];
    const float o2 = xq2 + acc[2];
    const float o3 = xq3 + acc[3];
    if (it < 17){
      const int n1 = n0 + 64;
      ub0 = *(const bf16x8*)&Ubf[(n1 + m)*DD +      quad*8];
      ub1 = *(const bf16x8*)&Ubf[(n1 + m)*DD + 32 + quad*8];
      xq0 = x[(row0 + q4 + 0)*NN + n1 + m];
      xq1 = x[(row0 + q4 + 1)*NN + n1 + m];
      xq2 = x[(row0 + q4 + 2)*NN + n1 + m];
      xq3 = x[(row0 + q4 + 3)*NN + n1 + m];
    }
    out[(row0 + q4 + 0)*NN + n0 + m] = o0;
    out[(row0 + q4 + 1)*NN + n0 + m] = o1;
    out[(row0 + q4 + 2)*NN + n0 + m] = o2;
    out[(row0 + q4 + 3)*NN + n0 + m] = o3;
  }
}

extern "C" void kernel_launch(void* const* d_in, const int* in_sizes, int n_in,
                              void* d_out, int out_size, void* d_ws, size_t ws_size,
                              hipStream_t stream) {
  const float* x    = (const float*)d_in[0];
  const float* cond = (const float*)d_in[1];
  const float* P    = (const float*)d_in[2];
  const float* W    = (const float*)d_in[3];
  const float* bias = (const float*)d_in[4];
  float* out = (float*)d_out;
  float* ws  = (float*)d_ws;

  float* Gpart = ws;                      // 6*4096 = 24576 floats
  float* Rbuf  = ws + 24576;              // 4096
  float* vpart = ws + 28672;              // 6*16*2016 = 193536
  float* Mg    = ws + 222208;             // 16*4096 = 65536
  short* Ubf   = (short*)(ws + 287744);   // 1152*64 bf16 = 36864 floats
  short* Utbf  = (short*)(ws + 324608);   // 64*1152 bf16 = 36864 floats
  short* wg    = (short*)(ws + 361472);   // 16384*64 bf16 = 524288 floats

  hipLaunchKernelGGL(k_pre,   dim3(VBLKS + GPARTS), dim3(256), 0, stream, cond, W, vpart, P, Gpart);
  hipLaunchKernelGGL(k_setup, dim3(NB + 1),         dim3(256), 0, stream, Gpart, P, Rbuf, vpart, bias, Mg);
  hipLaunchKernelGGL(k_solveU,dim3(NN/DD),          dim3(64),  0, stream, P, Rbuf, Ubf, Utbf);
  hipLaunchKernelGGL(k_zw,    dim3(NROWS/64),       dim3(512), 0, stream, x, Utbf, Mg, wg);
  hipLaunchKernelGGL(k_out,   dim3(NROWS/16),       dim3(256), 0, stream, x, Ubf, wg, out);
}

// Round 4
// 263.727 us; speedup vs baseline: 2.0622x; 2.0622x over previous
//
#include <hip/hip_runtime.h>
#include <math.h>

#define NN 1152
#define DD 64
#define NSK 2016
#define NB 16
#define NROWS (NB*1024)
#define GPARTS 6
#define KPARTS 6
#define VNBLK 32
#define VBLKS (VNBLK*KPARTS)   // 192 vproj GEMM blocks

typedef short bf16x8 __attribute__((ext_vector_type(8)));
typedef short bf16x4 __attribute__((ext_vector_type(4)));
typedef float f32x4  __attribute__((ext_vector_type(4)));

__device__ __forceinline__ short bfr(float f){
  unsigned u = __float_as_uint(f);
  u += 0x7fffu + ((u >> 16) & 1u);
  return (short)(u >> 16);
}

// ================= K1: vproj as MFMA GEMM (blocks 0..191) + partial gram (192..197) ==========
__global__ __launch_bounds__(256) void k_pre(const float* __restrict__ cond, const float* __restrict__ W,
                                             float* __restrict__ vpart,
                                             const float* __restrict__ P, float* __restrict__ Gpart){
  __shared__ float Ps[64*68];
  const int tid = threadIdx.x;
  if (blockIdx.x < VBLKS){
    const int nb = blockIdx.x / KPARTS;
    const int kp = blockIdx.x % KPARTS;
    const int lane = tid & 63, wid = tid >> 6;
    const int m = lane & 15, quad = lane >> 4;
    const int n0 = nb*64 + wid*16;
    if (n0 >= NSK) return;            // tail tiles of last N-block
    f32x4 acc = {0.f,0.f,0.f,0.f};
    const float* crow = &cond[m*NN + kp*192 + quad*8];
    const float* wrow = &W[(n0 + m)*NN + kp*192 + quad*8];
    #pragma unroll
    for (int c = 0; c < 6; ++c){
      const float4 ca = *(const float4*)(crow + c*32);
      const float4 cb = *(const float4*)(crow + c*32 + 4);
      const float4 wa = *(const float4*)(wrow + c*32);
      const float4 wb = *(const float4*)(wrow + c*32 + 4);
      bf16x8 a, b;
      const float cv[8] = {ca.x,ca.y,ca.z,ca.w,cb.x,cb.y,cb.z,cb.w};
      const float wv[8] = {wa.x,wa.y,wa.z,wa.w,wb.x,wb.y,wb.z,wb.w};
      #pragma unroll
      for (int j = 0; j < 8; ++j){
        const float xv = cv[j];
        a[j] = bfr(xv / (1.f + __expf(-xv)));
        b[j] = bfr(wv[j]);
      }
      acc = __builtin_amdgcn_mfma_f32_16x16x32_bf16(a, b, acc, 0, 0, 0);
    }
    #pragma unroll
    for (int r = 0; r < 4; ++r)
      vpart[(kp*16 + quad*4 + r)*NSK + n0 + m] = acc[r];
  } else {
    // ---- partial gram: block p covers rows p*192 .. p*192+191 (3 chunks of 64)
    const int p = blockIdx.x - VBLKS;
    const int lr = tid >> 4, lc = (tid & 15) * 4;
    const int ti = tid >> 4, tj = tid & 15;
    float acc[4][4];
    #pragma unroll
    for (int i=0;i<4;++i){
      #pragma unroll
      for (int j=0;j<4;++j) acc[i][j]=0.f;
    }
    for (int ch = 0; ch < 3; ++ch){
      const int nn0 = p*192 + ch*64;
      __syncthreads();
      #pragma unroll
      for (int ii = 0; ii < 4; ++ii){
        const float4 pv = *(const float4*)&P[(nn0 + lr + 16*ii)*DD + lc];
        *(float4*)&Ps[(lr + 16*ii)*68 + lc] = pv;
      }
      __syncthreads();
      for (int r = 0; r < 64; ++r){
        const float4 a = *(const float4*)&Ps[r*68 + ti*4];
        const float4 b = *(const float4*)&Ps[r*68 + tj*4];
        const float av[4] = {a.x,a.y,a.z,a.w};
        const float bv[4] = {b.x,b.y,b.z,b.w};
        #pragma unroll
        for (int i=0;i<4;++i){
          #pragma unroll
          for (int j=0;j<4;++j) acc[i][j] = fmaf(av[i], bv[j], acc[i][j]);
        }
      }
    }
    float* g = &Gpart[p*DD*DD];
    #pragma unroll
    for (int i=0;i<4;++i){
      float4 ov = make_float4(acc[i][0], acc[i][1], acc[i][2], acc[i][3]);
      *(float4*)&g[(ti*4+i)*DD + tj*4] = ov;
    }
  }
}

// ================= K2: register-wave QR (block 16) + fp32 expm, 512 threads (blocks 0..15) ==========
__device__ void qr_wave(const float* __restrict__ Gpart, const float* __restrict__ P,
                        float* __restrict__ Rout){
  const int j = threadIdx.x; // lane = column j
  float Gc[DD], Wc[DD], Rc[DD];
  #pragma unroll
  for (int i = 0; i < DD; ++i){
    float g = 0.f;
    #pragma unroll
    for (int p = 0; p < GPARTS; ++p) g += Gpart[p*4096 + i*DD + j];
    Gc[i] = g;
    Wc[i] = P[i*DD + j];
  }
  #pragma unroll
  for (int k = 0; k < DD; ++k){
    const float gkk = __shfl(Gc[k], k);
    const float wkk = __shfl(Wc[k], k);
    const float beta = (wkk >= 0.f) ? -sqrtf(gkk) : sqrtf(gkk);
    const float wkj = Wc[k];
    const float dj  = Gc[k] - beta*wkj;
    const float cj  = dj / (beta*(beta - wkk));
    float rkj = wkj + dj/beta;
    if (j == k) rkj = beta;
    if (j <  k) rkj = 0.f;
    Rc[k] = rkj;
    #pragma unroll
    for (int i = k+1; i < DD; ++i){
      const float wik = __shfl(Wc[i], k);   // column k of Wt lives in lane k
      const float rki = __shfl(rkj, i);     // R[k][i] lives in lane i
      Wc[i] = fmaf(-cj,  wik, Wc[i]);
      Gc[i] = fmaf(-rki, rkj, Gc[i]);
    }
  }
  #pragma unroll
  for (int i = 0; i < DD; ++i) Rout[i*DD + j] = Rc[i];
}

// 512-thread 64x64 fp32 matmul: wave w owns rows (w&3)*16, cols (w>>2)*32;
// each thread: 2 rows x 4 cols. C never aliases A or B (A==B allowed).
__device__ __forceinline__ void mmul68(const float* __restrict__ A, const float* __restrict__ B,
                                       float* __restrict__ C, int tid){
  __syncthreads();
  const int w = tid >> 6, lane = tid & 63;
  const int r0 = (w & 3) * 16 + (lane >> 3) * 2;
  const int c0 = (w >> 2) * 32 + (lane & 7) * 4;
  float acc[2][4];
  #pragma unroll
  for (int i=0;i<2;++i){
    #pragma unroll
    for (int j=0;j<4;++j) acc[i][j]=0.f;
  }
  for (int kq = 0; kq < 16; ++kq){
    float4 b[4];
    #pragma unroll
    for (int kk=0;kk<4;++kk) b[kk] = *(const float4*)&B[(kq*4+kk)*68 + c0];
    const float4 a0 = *(const float4*)&A[(r0    )*68 + kq*4];
    const float4 a1 = *(const float4*)&A[(r0 + 1)*68 + kq*4];
    const float av0[4] = {a0.x,a0.y,a0.z,a0.w};
    const float av1[4] = {a1.x,a1.y,a1.z,a1.w};
    #pragma unroll
    for (int kk=0;kk<4;++kk){
      acc[0][0] = fmaf(av0[kk], b[kk].x, acc[0][0]);
      acc[0][1] = fmaf(av0[kk], b[kk].y, acc[0][1]);
      acc[0][2] = fmaf(av0[kk], b[kk].z, acc[0][2]);
      acc[0][3] = fmaf(av0[kk], b[kk].w, acc[0][3]);
      acc[1][0] = fmaf(av1[kk], b[kk].x, acc[1][0]);
      acc[1][1] = fmaf(av1[kk], b[kk].y, acc[1][1]);
      acc[1][2] = fmaf(av1[kk], b[kk].z, acc[1][2]);
      acc[1][3] = fmaf(av1[kk], b[kk].w, acc[1][3]);
    }
  }
  *(float4*)&C[(r0    )*68 + c0] = make_float4(acc[0][0],acc[0][1],acc[0][2],acc[0][3]);
  *(float4*)&C[(r0 + 1)*68 + c0] = make_float4(acc[1][0],acc[1][1],acc[1][2],acc[1][3]);
  __syncthreads();
}

__global__ __launch_bounds__(512,1) void k_setup(const float* __restrict__ Gpart, const float* __restrict__ P,
                                                 float* __restrict__ Rout,
                                                 const float* __restrict__ vpart, const float* __restrict__ bias,
                                                 float* __restrict__ Mg){
  __shared__ float Bs[64*68], B2[64*68], B3[64*68], Tb[64*68], Xb[64*68];
  __shared__ float red[512];
  __shared__ float scl_s;
  __shared__ int   ssh_s;
  const int tid = threadIdx.x;
  if (blockIdx.x == NB){
    if (tid >= 64) return;
    qr_wave(Gpart, P, Rout);
    return;
  }
  const int b = blockIdx.x;
  // build skew A (unscaled) into Xb; v reduced over K-partials + bias
  for (int idx = tid; idx < 64*64; idx += 512)
    Xb[(idx>>6)*68 + (idx&63)] = 0.f;
  __syncthreads();
  for (int idx = tid; idx < NSK; idx += 512){
    int i = (int)((127.0f - sqrtf(16129.0f - 8.0f*(float)idx)) * 0.5f);
    while (i*(127 - i)/2 > idx) --i;
    while ((i+1)*(127 - (i+1))/2 <= idx) ++i;
    const int jj = idx - i*(127 - i)/2 + i + 1;
    float val = bias[idx];
    #pragma unroll
    for (int p = 0; p < KPARTS; ++p) val += vpart[(p*16 + b)*NSK + idx];
    Xb[i*68 + jj] = val;
    Xb[jj*68 + i] = -val;
  }
  __syncthreads();
  // ---- 1-norm -> scaling (parallel: 8 row-groups x 64 cols, then wave-0 max)
  {
    const int c = tid & 63, g = tid >> 6;
    float s = 0.f;
    for (int r = g*8; r < g*8 + 8; ++r) s += fabsf(Xb[r*68 + c]);
    red[g*64 + c] = s;
    __syncthreads();
    if (tid < 64){
      float cs = 0.f;
      #pragma unroll
      for (int g2 = 0; g2 < 8; ++g2) cs += red[g2*64 + tid];
      #pragma unroll
      for (int off = 32; off > 0; off >>= 1) cs = fmaxf(cs, __shfl_xor(cs, off));
      if (tid == 0){
        int s2 = 0; float scale = 1.f;
        float nrm = cs;
        while (nrm > 1.0f && s2 < 40){ nrm *= 0.5f; scale *= 0.5f; ++s2; }
        ssh_s = s2; scl_s = scale;
      }
    }
    __syncthreads();
  }
  const float scale = scl_s;
  const int   sq    = ssh_s;
  for (int idx = tid; idx < 64*64; idx += 512){
    const int i = idx>>6, jj = idx&63;
    Bs[i*68 + jj] = Xb[i*68 + jj] * scale;
  }
  // B2 = B*B ; B3 = B2*B
  mmul68(Bs, Bs, B2, tid);
  mmul68(B2, Bs, B3, tid);
  for (int idx = tid; idx < 64*64; idx += 512){
    const int i = idx>>6, jj = idx&63;
    const int o = i*68 + jj;
    Tb[o] = (i==jj ? (1.f/720.f) : 0.f) + Bs[o]*(1.f/5040.f) + B2[o]*(1.f/40320.f) + B3[o]*(1.f/362880.f);
  }
  mmul68(B3, Tb, Xb, tid);              // X = B3*T
  for (int idx = tid; idx < 64*64; idx += 512){
    const int i = idx>>6, jj = idx&63;
    const int o = i*68 + jj;
    Xb[o] += (i==jj ? (1.f/6.f) : 0.f) + Bs[o]*(1.f/24.f) + B2[o]*(1.f/120.f);
  }
  mmul68(B3, Xb, Tb, tid);              // T = B3*X
  for (int idx = tid; idx < 64*64; idx += 512){
    const int i = idx>>6, jj = idx&63;
    const int o = i*68 + jj;
    Tb[o] += (i==jj ? 1.f : 0.f) + Bs[o] + B2[o]*0.5f;   // + G0
  }
  // squarings
  float* cur = Tb;
  float* oth = Xb;
  for (int r = 0; r < sq; ++r){
    mmul68(cur, cur, oth, tid);
    float* t = cur; cur = oth; oth = t;
  }
  for (int idx = tid; idx < 64*64; idx += 512){
    const int i = idx>>6, jj = idx&63;
    Mg[b*4096 + idx] = cur[i*68 + jj] - (i==jj ? 1.f : 0.f);
  }
}

// ================= K3: solve u.R = p per row; emit U bf16 (row-major) + U^T bf16 ==========
__global__ __launch_bounds__(64) void k_solveU(const float* __restrict__ P, const float* __restrict__ Rg,
                                               short* __restrict__ Ubf, short* __restrict__ Utbf){
  __shared__ float Rs[DD*DD];
  __shared__ float Ps[DD*65];
  __shared__ float rd[DD];
  const int tid = threadIdx.x;
  const int n0 = blockIdx.x * DD;
  for (int r = 0; r < DD; ++r){
    Rs[r*DD + tid] = Rg[r*DD + tid];
    Ps[r*65 + tid] = P[(n0 + r)*DD + tid];
  }
  rd[tid] = 1.f / Rg[tid*DD + tid];
  __syncthreads();
  float u[DD];
  #pragma unroll
  for (int j = 0; j < DD; ++j){
    float s0 = Ps[tid*65 + j], s1 = 0.f;
    #pragma unroll
    for (int l = 0; l + 1 < j; l += 2){
      s0 = fmaf(-u[l],   Rs[l*DD + j],     s0);
      s1 = fmaf(-u[l+1], Rs[(l+1)*DD + j], s1);
    }
    if (j & 1) s0 = fmaf(-u[j-1], Rs[(j-1)*DD + j], s0);
    u[j] = (s0 + s1) * rd[j];
  }
  #pragma unroll
  for (int d = 0; d < DD; ++d)
    Utbf[d*NN + n0 + tid] = bfr(u[d]);
  #pragma unroll
  for (int j8 = 0; j8 < 8; ++j8){
    bf16x8 pk;
    #pragma unroll
    for (int jj = 0; jj < 8; ++jj) pk[jj] = bfr(u[j8*8 + jj]);
    *(bf16x8*)&Ubf[(n0 + tid)*DD + j8*8] = pk;
  }
}

// ================= K4a: z = x.U ; w = z.(R-I) -> wg bf16 ==========
__global__ __launch_bounds__(512,1) void k_zw(const float* __restrict__ x, const short* __restrict__ Utbf,
                                              const float* __restrict__ Mg, short* __restrict__ wg){
  __shared__ float zs[64*68];
  __shared__ float Ms[64*68];
  const int tid  = threadIdx.x;
  const int lane = tid & 63, wid = tid >> 6;
  const int row0 = blockIdx.x * 64;
  const int bb   = row0 >> 10;
  const int m    = lane & 15, quad = lane >> 4;
  for (int idx = tid; idx < 64*64; idx += 512)
    Ms[(idx>>6)*68 + (idx&63)] = Mg[bb*4096 + idx];

  // ---- phase 1: z = x_tile @ U   (wave: rows (wid&3)*16, cols (wid>>2)*32)
  const int r0 = (wid & 3) * 16;
  const int c0 = (wid >> 2) * 32;
  f32x4 acc0 = {0.f,0.f,0.f,0.f}, acc1 = {0.f,0.f,0.f,0.f};
  const float* xrow = &x[(row0 + r0 + m)*NN + quad*8];
  const short* ut0  = &Utbf[(c0      + m)*NN + quad*8];
  const short* ut1  = &Utbf[(c0 + 16 + m)*NN + quad*8];
  float4 xa = *(const float4*)(xrow);
  float4 xb = *(const float4*)(xrow + 4);
  bf16x8 b0 = *(const bf16x8*)(ut0);
  bf16x8 b1 = *(const bf16x8*)(ut1);
  for (int kc = 0; kc < NN; kc += 32){
    float4 nxa, nxb; bf16x8 nb0, nb1;
    if (kc + 32 < NN){
      nxa = *(const float4*)(xrow + kc + 32);
      nxb = *(const float4*)(xrow + kc + 36);
      nb0 = *(const bf16x8*)(ut0 + kc + 32);
      nb1 = *(const bf16x8*)(ut1 + kc + 32);
    }
    bf16x8 a;
    a[0]=bfr(xa.x); a[1]=bfr(xa.y); a[2]=bfr(xa.z); a[3]=bfr(xa.w);
    a[4]=bfr(xb.x); a[5]=bfr(xb.y); a[6]=bfr(xb.z); a[7]=bfr(xb.w);
    acc0 = __builtin_amdgcn_mfma_f32_16x16x32_bf16(a, b0, acc0, 0, 0, 0);
    acc1 = __builtin_amdgcn_mfma_f32_16x16x32_bf16(a, b1, acc1, 0, 0, 0);
    xa = nxa; xb = nxb; b0 = nb0; b1 = nb1;
  }
  #pragma unroll
  for (int q = 0; q < 4; ++q){
    zs[(r0 + quad*4 + q)*68 + c0      + m] = acc0[q];
    zs[(r0 + quad*4 + q)*68 + c0 + 16 + m] = acc1[q];
  }
  __syncthreads();

  // ---- phase 2: w = z @ M (fp32), store bf16 to global
  const int r  = tid >> 3;
  const int cc = (tid & 7) * 8;
  float w0[8];
  #pragma unroll
  for (int jj = 0; jj < 8; ++jj) w0[jj] = 0.f;
  for (int k = 0; k < 64; ++k){
    const float zr = zs[r*68 + k];
    const float4 m0 = *(const float4*)&Ms[k*68 + cc];
    const float4 m1 = *(const float4*)&Ms[k*68 + cc + 4];
    w0[0] = fmaf(zr, m0.x, w0[0]); w0[1] = fmaf(zr, m0.y, w0[1]);
    w0[2] = fmaf(zr, m0.z, w0[2]); w0[3] = fmaf(zr, m0.w, w0[3]);
    w0[4] = fmaf(zr, m1.x, w0[4]); w0[5] = fmaf(zr, m1.y, w0[5]);
    w0[6] = fmaf(zr, m1.z, w0[6]); w0[7] = fmaf(zr, m1.w, w0[7]);
  }
  bf16x8 pk;
  #pragma unroll
  for (int jj = 0; jj < 8; ++jj) pk[jj] = bfr(w0[jj]);
  *(bf16x8*)&wg[(row0 + r)*DD + cc] = pk;
}

// ================= K4b: out = x + w @ U^T  (pure streaming) ==========
__global__ __launch_bounds__(256) void k_out(const float* __restrict__ x, const short* __restrict__ Ubf,
                                             const short* __restrict__ wg, float* __restrict__ out){
  const int tid  = threadIdx.x;
  const int lane = tid & 63, wid = tid >> 6;
  const int row0 = blockIdx.x * 16;
  const int m    = lane & 15, quad = lane >> 4;
  const int q4   = quad * 4;
  bf16x8 wa0 = *(const bf16x8*)&wg[(row0 + m)*DD +      quad*8];
  bf16x8 wa1 = *(const bf16x8*)&wg[(row0 + m)*DD + 32 + quad*8];
  bf16x8 ub0 = *(const bf16x8*)&Ubf[(wid*16 + m)*DD +      quad*8];
  bf16x8 ub1 = *(const bf16x8*)&Ubf[(wid*16 + m)*DD + 32 + quad*8];
  float xq0 = x[(row0 + q4 + 0)*NN + wid*16 + m];
  float xq1 = x[(row0 + q4 + 1)*NN + wid*16 + m];
  float xq2 = x[(row0 + q4 + 2)*NN + wid*16 + m];
  float xq3 = x[(row0 + q4 + 3)*NN + wid*16 + m];
  for (int it = 0; it < 18; ++it){
    const int n0 = (wid + 4*it) * 16;
    f32x4 acc = {0.f,0.f,0.f,0.f};
    acc = __builtin_amdgcn_mfma_f32_16x16x32_bf16(wa0, ub0, acc, 0, 0, 0);
    acc = __builtin_amdgcn_mfma_f32_16x16x32_bf16(wa1, ub1, acc, 0, 0, 0);
    const float o0 = xq0 + acc[0];
    const float o1 = xq1 + acc[1];
    const float o2 = xq2 + acc[2];
    const float o3 = xq3 + acc[3];
    if (it < 17){
      const int n1 = n0 + 64;
      ub0 = *(const bf16x8*)&Ubf[(n1 + m)*DD +      quad*8];
      ub1 = *(const bf16x8*)&Ubf[(n1 + m)*DD + 32 + quad*8];
      xq0 = x[(row0 + q4 + 0)*NN + n1 + m];
      xq1 = x[(row0 + q4 + 1)*NN + n1 + m];
      xq2 = x[(row0 + q4 + 2)*NN + n1 + m];
      xq3 = x[(row0 + q4 + 3)*NN + n1 + m];
    }
    out[(row0 + q4 + 0)*NN + n0 + m] = o0;
    out[(row0 + q4 + 1)*NN + n0 + m] = o1;
    out[(row0 + q4 + 2)*NN + n0 + m] = o2;
    out[(row0 + q4 + 3)*NN + n0 + m] = o3;
  }
}

extern "C" void kernel_launch(void* const* d_in, const int* in_sizes, int n_in,
                              void* d_out, int out_size, void* d_ws, size_t ws_size,
                              hipStream_t stream) {
  const float* x    = (const float*)d_in[0];
  const float* cond = (const float*)d_in[1];
  const float* P    = (const float*)d_in[2];
  const float* W    = (const float*)d_in[3];
  const float* bias = (const float*)d_in[4];
  float* out = (float*)d_out;
  float* ws  = (float*)d_ws;

  float* Gpart = ws;                      // 6*4096 = 24576 floats
  float* Rbuf  = ws + 24576;              // 4096
  float* vpart = ws + 28672;              // 6*16*2016 = 193536
  float* Mg    = ws + 222208;             // 16*4096 = 65536
  short* Ubf   = (short*)(ws + 287744);   // 1152*64 bf16 = 36864 floats
  short* Utbf  = (short*)(ws + 324608);   // 64*1152 bf16 = 36864 floats
  short* wg    = (short*)(ws + 361472);   // 16384*64 bf16 = 524288 floats

  hipLaunchKernelGGL(k_pre,   dim3(VBLKS + GPARTS), dim3(256), 0, stream, cond, W, vpart, P, Gpart);
  hipLaunchKernelGGL(k_setup, dim3(NB + 1),         dim3(512), 0, stream, Gpart, P, Rbuf, vpart, bias, Mg);
  hipLaunchKernelGGL(k_solveU,dim3(NN/DD),          dim3(64),  0, stream, P, Rbuf, Ubf, Utbf);
  hipLaunchKernelGGL(k_zw,    dim3(NROWS/64),       dim3(512), 0, stream, x, Utbf, Mg, wg);
  hipLaunchKernelGGL(k_out,   dim3(NROWS/16),       dim3(256), 0, stream, x, Ubf, wg, out);
}